// Round 9
// baseline (616.662 us; speedup 1.0000x reference)
//
#include <hip/hip_runtime.h>

// CapsuleLayer dynamic routing, MI355X fp32.
// x: [B=64, N=2048, I=8], W: [J=32, N=2048, D=16, I=8], out v: [B=64, J=32, D=16]
//
// b_t = u_hat . (v_0+...+v_{t-1})  =>  u_hat (256 MB) never materialized;
// each phase recomputes it in registers from x + W (L2-resident via XCD
// swizzle, FETCH ~21 MB/phase). R9: R8's atomics regressed (device-scope
// fp32 atomics bypass XCD L2 -> 32 MB HBM RMW traffic) -> back to partial
// stores + reduce (R5-proven). New: BG=4 / 2048 blocks / launch_bounds(256,6)
// = 6 blocks/CU TLP to fill the x s_load stall gaps (R4-R8 all showed
// VALUBusy ~38% @ occupancy ~31% with VGPR 48 — occupancy was the lever),
// + i-pair pk_fma packing (no wk v_movs, lower VGPR), + restored W prefetch.

#define BB_ 64
#define NN_ 2048
#define II_ 8
#define JJ_ 32
#define DD_ 16
#define NCHUNKS 128
#define CHUNK 16       /* n's per block */
#define BG 4           /* b's per block */
#define NBG (BB_ / BG) /* 16 */
#define NLB 2          /* n's per barrier round */
#define EPS_ 1e-7f
#define OUT_ELEMS (BB_ * JJ_ * DD_)                /* 32768 */
#define PARTIAL_FLOATS (NCHUNKS * OUT_ELEMS)       /* 4M floats = 16.8 MB */

typedef __attribute__((ext_vector_type(2))) float v2f;

// DPP helpers (VALU-pipe cross-lane). CTRL must be an immediate.
template <int CTRL>
__device__ __forceinline__ float dpp_add(float v) {
  const int s = __builtin_amdgcn_update_dpp(
      0, __builtin_bit_cast(int, v), CTRL, 0xf, 0xf, true);
  return v + __builtin_bit_cast(float, s);
}
#define DPP_QP_XOR1 0xB1      /* quad_perm [1,0,3,2]  : lane ^ 1 */
#define DPP_QP_XOR2 0x4E      /* quad_perm [2,3,0,1]  : lane ^ 2 */
#define DPP_HALF_MIRROR 0x141 /* mirror within 8      : lane ^ 7 */
#define DPP_ROR8 0x128        /* row_ror:8 (16-lane)  : lane ^ 8 */

// Load one n's 16 W floats (d0 i0..7, d1 i0..7) as 8 i-pairs, reg-aligned:
// float4 quads split into adjacent v2f pairs — no packing moves.
__device__ __forceinline__ void load_w8(v2f* w, const float* ptr) {
  const float4* q4 = (const float4*)ptr;
  const float4 t0 = q4[0], t1 = q4[1], t2 = q4[2], t3 = q4[3];
  w[0] = v2f{t0.x, t0.y};
  w[1] = v2f{t0.z, t0.w};
  w[2] = v2f{t1.x, t1.y};
  w[3] = v2f{t1.z, t1.w};
  w[4] = v2f{t2.x, t2.y};
  w[5] = v2f{t2.z, t2.w};
  w[6] = v2f{t3.x, t3.y};
  w[7] = v2f{t3.z, t3.w};
}

// 256 threads = (j = tid>>3) x (p = tid&7); thread owns output cap j, dims
// d in {2p,2p+1}, for 4 b's. blockIdx = bg*NCHUNKS + chunk so blockIdx%8 ==
// chunk%8 -> all 16 blocks sharing a W chunk-slab (256 KB) land on one XCD
// (16 slabs x 256 KB = 4 MB = one L2).
template <int PHASE>
__global__ __launch_bounds__(256, 6) void caps_phase(
    const float* __restrict__ x, const float* __restrict__ W,
    const float* __restrict__ V, float* __restrict__ partial) {
  const int tid = threadIdx.x;
  const int j = tid >> 3;
  const int p = tid & 7;
  const int chunk = blockIdx.x & (NCHUNKS - 1);
  const int bg = blockIdx.x >> 7;
  const int b0 = bg * BG;
  const int n0 = chunk * CHUNK;

  __shared__ float lmat[NLB][BG][JJ_];
  __shared__ float cmat[NLB][BG][JJ_];

  // V fragment: V[b0+b][j][2p..2p+1] for 4 b's.
  float v0r[BG], v1r[BG];
  if (PHASE > 0) {
#pragma unroll
    for (int b = 0; b < BG; ++b) {
      const float2 vv =
          *(const float2*)&V[((size_t)(b0 + b) * JJ_ + j) * DD_ + 2 * p];
      v0r[b] = vv.x;
      v1r[b] = vv.y;
    }
  }

  float s0[BG], s1[BG];
#pragma unroll
  for (int b = 0; b < BG; ++b) {
    s0[b] = 0.f;
    s1[b] = 0.f;
  }

  // W[j][n][d][i]: thread reads 16 consecutive floats at j*262144 + n*128 + p*16.
  const float* wp = W + (size_t)j * (NN_ * DD_ * II_) +
                    (size_t)n0 * (DD_ * II_) + (size_t)p * 16;

  // W double-buffer, one NLB batch deep.
  v2f wcur[NLB][8];
#pragma unroll
  for (int q = 0; q < NLB; ++q) load_w8(wcur[q], wp + (size_t)q * (DD_ * II_));

  for (int rr = 0; rr < CHUNK / NLB; ++rr) {
    const int nl = rr * NLB;
    // Prefetch next batch (wrap on last round: harmless L2-hot reload).
    v2f wnext[NLB][8];
#pragma unroll
    for (int q = 0; q < NLB; ++q) {
      const int nn = (nl + NLB + q) & (CHUNK - 1);
      load_w8(wnext[q], wp + (size_t)nn * (DD_ * II_));
    }

    float u0[NLB][BG], u1[NLB][BG];
#pragma unroll
    for (int q = 0; q < NLB; ++q) {
      const int n = n0 + nl + q;
#pragma unroll
      for (int b = 0; b < BG; ++b) {
        // Wave-uniform x row: scalar-load path (s_load_dwordx4 x2), used as
        // sgpr-pair operands of v_pk_fma_f32 (1 sgpr src per inst: legal).
        const float4* __restrict__ xr =
            (const float4*)(x + ((size_t)(b0 + b) * NN_ + n) * II_);
        const float4 xa = xr[0];
        const float4 xb = xr[1];
        const v2f xp0 = {xa.x, xa.y}, xp1 = {xa.z, xa.w};
        const v2f xp2 = {xb.x, xb.y}, xp3 = {xb.z, xb.w};
        v2f a0 = wcur[q][0] * xp0;
        a0 += wcur[q][1] * xp1;
        a0 += wcur[q][2] * xp2;
        a0 += wcur[q][3] * xp3;
        v2f a1 = wcur[q][4] * xp0;
        a1 += wcur[q][5] * xp1;
        a1 += wcur[q][6] * xp2;
        a1 += wcur[q][7] * xp3;
        u0[q][b] = a0.x + a0.y;  // u_hat[d=2p]
        u1[q][b] = a1.x + a1.y;  // u_hat[d=2p+1]
      }
    }

    if (PHASE == 0) {
      // softmax(0) over J is uniform -> plain sum (scale at store).
#pragma unroll
      for (int b = 0; b < BG; ++b) {
        s0[b] += u0[0][b] + u0[1][b];
        s1[b] += u1[0][b] + u1[1][b];
      }
    } else {
      // logits: 2-elem partial per lane, xor butterfly over the 8 p-lanes
      // (all lanes end with the full sum; p==0 stores).
#pragma unroll
      for (int q = 0; q < NLB; ++q)
#pragma unroll
        for (int b = 0; b < BG; ++b) {
          float lp = u0[q][b] * v0r[b] + u1[q][b] * v1r[b];
          lp = dpp_add<DPP_QP_XOR1>(lp);
          lp = dpp_add<DPP_QP_XOR2>(lp);
          lp = dpp_add<DPP_HALF_MIRROR>(lp);
          if (p == 0) lmat[q][b][j] = lp;
        }
      __syncthreads();
      // softmax over j: 2q x 4b x 32j = 256 entries, one per thread.
      // |logit| <= ~1.5: exp safe without max subtraction (validated R2-R8).
      {
        const int jj = tid & 31;
        const int bq = (tid >> 5) & 3;
        const int qq = tid >> 7;
        const float e0 = __expf(lmat[qq][bq][jj]);
        float m0 = e0;
        m0 = dpp_add<DPP_QP_XOR1>(m0);
        m0 = dpp_add<DPP_QP_XOR2>(m0);
        m0 = dpp_add<DPP_HALF_MIRROR>(m0);
        m0 = dpp_add<DPP_ROR8>(m0);
        m0 += __shfl_xor(m0, 16);
        cmat[qq][bq][jj] = e0 * __builtin_amdgcn_rcpf(m0);
      }
      __syncthreads();
#pragma unroll
      for (int q = 0; q < NLB; ++q)
#pragma unroll
        for (int b = 0; b < BG; ++b) {
          const float c = cmat[q][b][j];  // broadcast (all p-lanes same addr)
          s0[b] += c * u0[q][b];
          s1[b] += c * u1[q][b];
        }
      // no 3rd sync: next round's lmat writes are gated by the cmat barrier.
    }

#pragma unroll
    for (int q = 0; q < NLB; ++q)
#pragma unroll
      for (int k = 0; k < 8; ++k) wcur[q][k] = wnext[q][k];
  }

  const float scale = (PHASE == 0) ? (1.0f / 32.0f) : 1.0f;
#pragma unroll
  for (int b = 0; b < BG; ++b) {
    const size_t off =
        ((size_t)chunk * BB_ + (b0 + b)) * (JJ_ * DD_) + j * DD_ + 2 * p;
    *(float2*)&partial[off] = make_float2(s0[b] * scale, s1[b] * scale);
  }
}

// Reduce over chunks + squash. MODE 0: V = v ; 1: V += v ; 2: out = v.
// 256 blocks x 128 threads (all CUs).
template <int MODE>
__global__ __launch_bounds__(128) void caps_reduce(
    const float* __restrict__ partial, float* __restrict__ V,
    float* __restrict__ out) {
  const int t = blockIdx.x * 128 + threadIdx.x;  // [0, B*J*D)
  float s = 0.f;
#pragma unroll 8
  for (int c = 0; c < NCHUNKS; ++c)
    s += partial[(size_t)c * OUT_ELEMS + t];
  // sum of squares over d (16 consecutive lanes = one (b,j))
  float ss = s * s;
  ss += __shfl_xor(ss, 1);
  ss += __shfl_xor(ss, 2);
  ss += __shfl_xor(ss, 4);
  ss += __shfl_xor(ss, 8);
  const float v = s / sqrtf(ss + EPS_);
  if (MODE == 0)
    V[t] = v;
  else if (MODE == 1)
    V[t] += v;
  else
    out[t] = v;
}

extern "C" void kernel_launch(void* const* d_in, const int* in_sizes, int n_in,
                              void* d_out, int out_size, void* d_ws,
                              size_t ws_size, hipStream_t stream) {
  const float* x = (const float*)d_in[0];
  const float* W = (const float*)d_in[1];
  float* out = (float*)d_out;
  float* partial = (float*)d_ws;        // 16.8 MB
  float* V = partial + PARTIAL_FLOATS;  // 128 KB

  const dim3 kgrid(NBG * NCHUNKS);   // 2048 blocks x 256 threads
  const dim3 rgrid(OUT_ELEMS / 128); // 256 blocks x 128 threads

  caps_phase<0><<<kgrid, 256, 0, stream>>>(x, W, nullptr, partial);
  caps_reduce<0><<<rgrid, 128, 0, stream>>>(partial, V, out);
  caps_phase<1><<<kgrid, 256, 0, stream>>>(x, W, V, partial);
  caps_reduce<1><<<rgrid, 128, 0, stream>>>(partial, V, out);
  caps_phase<2><<<kgrid, 256, 0, stream>>>(x, W, V, partial);
  caps_reduce<2><<<rgrid, 128, 0, stream>>>(partial, V, out);
}

// Round 10
// 201.216 us; speedup vs baseline: 3.0647x; 3.0647x over previous
//
#include <hip/hip_runtime.h>

// CapsuleLayer dynamic routing, MI355X fp32.
// x: [B=64, N=2048, I=8], W: [J=32, N=2048, D=16, I=8], out v: [B=64, J=32, D=16]
//
// b_t = u_hat . (v_0+...+v_{t-1})  =>  u_hat (256 MB) never materialized;
// each phase recomputes it in registers from x + W (L2-resident via XCD
// swizzle). R10 = R5's proven structure (177.9us) with ONE change: BG 8->4,
// grid 1024->2048 for 8 blocks/CU TLP. Occupancy comes from lower register
// NEED, not an allocator clamp — R9's launch_bounds(256,6) capped VGPR at 85
// under a ~110-VGPR kernel -> 760 MB/phase scratch spill, 280us/phase.

#define BB_ 64
#define NN_ 2048
#define II_ 8
#define JJ_ 32
#define DD_ 16
#define NCHUNKS 128
#define CHUNK 16       /* n's per block */
#define BG 4           /* b's per block */
#define NBG (BB_ / BG) /* 16 */
#define EPS_ 1e-7f
#define OUT_ELEMS (BB_ * JJ_ * DD_)          /* 32768 */
#define PARTIAL_FLOATS (NCHUNKS * OUT_ELEMS) /* 4M floats = 16.8 MB */

typedef __attribute__((ext_vector_type(2))) float v2f;

// DPP helpers (VALU-pipe cross-lane). CTRL must be an immediate.
template <int CTRL>
__device__ __forceinline__ float dpp_add(float v) {
  const int s = __builtin_amdgcn_update_dpp(
      0, __builtin_bit_cast(int, v), CTRL, 0xf, 0xf, true);
  return v + __builtin_bit_cast(float, s);
}
#define DPP_QP_XOR1 0xB1      /* quad_perm [1,0,3,2]  : lane ^ 1 */
#define DPP_QP_XOR2 0x4E      /* quad_perm [2,3,0,1]  : lane ^ 2 */
#define DPP_HALF_MIRROR 0x141 /* mirror within 8      : lane ^ 7 */
#define DPP_ROR8 0x128        /* row_ror:8 (16-lane)  : lane ^ 8 */

// Phase kernel: 256 threads = (j = tid>>3) x (p = tid&7); thread owns output
// cap j, dims d in {2p,2p+1}, for 4 b's. blockIdx = bg*NCHUNKS + chunk so
// blockIdx%8 == chunk%8 -> all 16 blocks sharing a W chunk-slab (256 KB)
// land on one XCD (16 slabs x 256 KB = 4 MB = one L2).
template <int PHASE>
__global__ __launch_bounds__(256, 4) void caps_phase(
    const float* __restrict__ x, const float* __restrict__ W,
    const float* __restrict__ V, float* __restrict__ partial) {
  const int tid = threadIdx.x;
  const int j = tid >> 3;
  const int p = tid & 7;
  const int chunk = blockIdx.x & (NCHUNKS - 1);
  const int bg = blockIdx.x >> 7;
  const int b0 = bg * BG;
  const int n0 = chunk * CHUNK;

  __shared__ float lmat[BG][JJ_];
  __shared__ float cmat[BG][JJ_];

  // V fragment: V[b0+b][j][2p..2p+1] for 4 b's.
  float v0r[BG], v1r[BG];
  if (PHASE > 0) {
#pragma unroll
    for (int b = 0; b < BG; ++b) {
      const float2 vv =
          *(const float2*)&V[((size_t)(b0 + b) * JJ_ + j) * DD_ + 2 * p];
      v0r[b] = vv.x;
      v1r[b] = vv.y;
    }
  }

  v2f s[BG];
#pragma unroll
  for (int b = 0; b < BG; ++b) s[b] = (v2f)(0.f);

  // W[j][n][d][i]: thread reads 16 consecutive floats at j*262144 + n*128 + p*16.
  const float* wp = W + (size_t)j * (NN_ * DD_ * II_) +
                    (size_t)n0 * (DD_ * II_) + (size_t)p * 16;
  float4 wc0 = ((const float4*)wp)[0];
  float4 wc1 = ((const float4*)wp)[1];
  float4 wc2 = ((const float4*)wp)[2];
  float4 wc3 = ((const float4*)wp)[3];

  for (int nl = 0; nl < CHUNK; ++nl) {
    const int n = n0 + nl;
    // Register double-buffer: prefetch next n's W while computing this one.
    const int nn = (nl + 1 < CHUNK) ? nl + 1 : nl;
    const float4* np_ = (const float4*)(wp + (size_t)nn * (DD_ * II_));
    const float4 wn0 = np_[0], wn1 = np_[1], wn2 = np_[2], wn3 = np_[3];

    // Pack W pairs {W[d0][i], W[d1][i]} once per nl -> v_pk_fma operands.
    v2f wk0 = {wc0.x, wc2.x}, wk1 = {wc0.y, wc2.y};
    v2f wk2 = {wc0.z, wc2.z}, wk3 = {wc0.w, wc2.w};
    v2f wk4 = {wc1.x, wc3.x}, wk5 = {wc1.y, wc3.y};
    v2f wk6 = {wc1.z, wc3.z}, wk7 = {wc1.w, wc3.w};

    v2f u[BG];
#pragma unroll
    for (int b = 0; b < BG; ++b) {
      // Wave-uniform x row (b, n uniform): scalar-load path, no LDS.
      const float4* __restrict__ xr =
          (const float4*)(x + ((size_t)(b0 + b) * NN_ + n) * II_);
      const float4 xa = xr[0];
      const float4 xb = xr[1];
      v2f acc = wk0 * xa.x;
      acc += wk1 * xa.y;
      acc += wk2 * xa.z;
      acc += wk3 * xa.w;
      acc += wk4 * xb.x;
      acc += wk5 * xb.y;
      acc += wk6 * xb.z;
      acc += wk7 * xb.w;
      u[b] = acc;
    }

    if (PHASE == 0) {
      // softmax(0) over J is uniform -> plain sum (scale at store).
#pragma unroll
      for (int b = 0; b < BG; ++b) s[b] += u[b];
    } else {
      // logits l[b][j] = sum_d u_hat*V: 2-elem partial per lane, then xor
      // butterfly over the 8 p-lanes (all lanes end with the full sum).
#pragma unroll
      for (int b = 0; b < BG; ++b) {
        float lp = u[b].x * v0r[b] + u[b].y * v1r[b];
        lp = dpp_add<DPP_QP_XOR1>(lp);
        lp = dpp_add<DPP_QP_XOR2>(lp);
        lp = dpp_add<DPP_HALF_MIRROR>(lp);
        if (p == 0) lmat[b][j] = lp;
      }
      __syncthreads();
      // softmax over j (32) x 4 b = 128 entries; threads 0..127 take one
      // each (upper half idles through the DPP ops harmlessly).
      // |logit| <= ~1.5: exp safe without max subtraction (validated R2-R9).
      {
        const int jj = tid & 31;
        const int bb = (tid >> 5) & 3;
        const float e0 = __expf(lmat[bb][jj]);
        float m0 = e0;
        m0 = dpp_add<DPP_QP_XOR1>(m0);
        m0 = dpp_add<DPP_QP_XOR2>(m0);
        m0 = dpp_add<DPP_HALF_MIRROR>(m0);
        m0 = dpp_add<DPP_ROR8>(m0);
        m0 += __shfl_xor(m0, 16);
        if (tid < 128) cmat[bb][jj] = e0 * __builtin_amdgcn_rcpf(m0);
      }
      __syncthreads();
#pragma unroll
      for (int b = 0; b < BG; ++b) {
        const float c = cmat[b][j];  // broadcast (all p-lanes same addr)
        s[b] += u[b] * c;            // one v_pk_fma
      }
      // no 3rd sync: next iter's lmat writes are gated by the cmat barrier.
    }

    wc0 = wn0;
    wc1 = wn1;
    wc2 = wn2;
    wc3 = wn3;
  }

  const float scale = (PHASE == 0) ? (1.0f / 32.0f) : 1.0f;
#pragma unroll
  for (int b = 0; b < BG; ++b) {
    const size_t off =
        ((size_t)chunk * BB_ + (b0 + b)) * (JJ_ * DD_) + j * DD_ + 2 * p;
    *(float2*)&partial[off] = make_float2(s[b].x * scale, s[b].y * scale);
  }
}

// Reduce over chunks + squash. MODE 0: V = v ; 1: V += v ; 2: out = v.
// 256 blocks x 128 threads (all CUs).
template <int MODE>
__global__ __launch_bounds__(128) void caps_reduce(
    const float* __restrict__ partial, float* __restrict__ V,
    float* __restrict__ out) {
  const int t = blockIdx.x * 128 + threadIdx.x;  // [0, B*J*D)
  float s = 0.f;
#pragma unroll 8
  for (int c = 0; c < NCHUNKS; ++c)
    s += partial[(size_t)c * OUT_ELEMS + t];
  // sum of squares over d (16 consecutive lanes = one (b,j))
  float ss = s * s;
  ss += __shfl_xor(ss, 1);
  ss += __shfl_xor(ss, 2);
  ss += __shfl_xor(ss, 4);
  ss += __shfl_xor(ss, 8);
  const float v = s / sqrtf(ss + EPS_);
  if (MODE == 0)
    V[t] = v;
  else if (MODE == 1)
    V[t] += v;
  else
    out[t] = v;
}

extern "C" void kernel_launch(void* const* d_in, const int* in_sizes, int n_in,
                              void* d_out, int out_size, void* d_ws,
                              size_t ws_size, hipStream_t stream) {
  const float* x = (const float*)d_in[0];
  const float* W = (const float*)d_in[1];
  float* out = (float*)d_out;
  float* partial = (float*)d_ws;        // 16.8 MB
  float* V = partial + PARTIAL_FLOATS;  // 128 KB

  const dim3 kgrid(NBG * NCHUNKS);    // 2048 blocks x 256 threads
  const dim3 rgrid(OUT_ELEMS / 128);  // 256 blocks x 128 threads

  caps_phase<0><<<kgrid, 256, 0, stream>>>(x, W, nullptr, partial);
  caps_reduce<0><<<rgrid, 128, 0, stream>>>(partial, V, out);
  caps_phase<1><<<kgrid, 256, 0, stream>>>(x, W, V, partial);
  caps_reduce<1><<<rgrid, 128, 0, stream>>>(partial, V, out);
  caps_phase<2><<<kgrid, 256, 0, stream>>>(x, W, V, partial);
  caps_reduce<2><<<rgrid, 128, 0, stream>>>(partial, V, out);
}